// Round 4
// baseline (256.648 us; speedup 1.0000x reference)
//
#include <hip/hip_runtime.h>
#include <hip/hip_bf16.h>

// Sizes fixed by the problem
constexpr int Bb = 32;
constexpr int Ll = 2048;
constexpr int Mm = 512;
constexpr int Hh = 512;
constexpr int Aa = 256;

typedef __attribute__((ext_vector_type(4))) float f32x4;
typedef __attribute__((ext_vector_type(8))) short short8;
typedef __attribute__((ext_vector_type(4))) unsigned short ushort4v;

__device__ __forceinline__ unsigned short f2bf(float f) {
    __hip_bfloat16 h = __float2bfloat16(f);   // RNE
    return *reinterpret_cast<unsigned short*>(&h);
}

__device__ __forceinline__ ushort4v cvt4(f32x4 v) {
    ushort4v o;
    o[0] = f2bf(v[0]); o[1] = f2bf(v[1]); o[2] = f2bf(v[2]); o[3] = f2bf(v[3]);
    return o;
}

// async global->LDS, 16B per lane; lds dest is wave-uniform base (+lane*16 by HW)
__device__ __forceinline__ void gload_lds16(const void* g, void* l) {
    __builtin_amdgcn_global_load_lds(
        (const __attribute__((address_space(1))) unsigned int*)g,
        (__attribute__((address_space(3))) unsigned int*)l, 16, 0, 0);
}

// ---------------- k_prep: fused W1m->bf16 permute + hb precompute ----------
// blocks 0..127: W1[:, :512] -> bf16 PERMUTED [ks][a][32] (contiguous 16KB
//                per K-step for k_score's global_load_lds staging)
// blocks 128..159: hb[b][a] = hidden[b,:].W1[a,512:] + b1[a]  (no atomics)
__global__ void k_prep(const float* __restrict__ W1, const float* __restrict__ hidden,
                       const float* __restrict__ b1,
                       unsigned short* __restrict__ W1mb, float* __restrict__ hb) {
    const int tid = threadIdx.x;
    if (blockIdx.x < 128) {
        int i = blockIdx.x * 256 + tid;            // 32768 threads, 4 floats each
        int a  = i >> 7;                           // 128 float4 per row
        int mq = (i & 127) << 2;
        f32x4 v = *reinterpret_cast<const f32x4*>(W1 + (size_t)a * (Mm + Hh) + mq);
        int ks = mq >> 5;                          // K-step (32 k per step)
        int kb = mq & 31;
        *reinterpret_cast<ushort4v*>(W1mb + (size_t)ks * (Aa * 32) + a * 32 + kb) = cvt4(v);
    } else {
        int b = blockIdx.x - 128;
        __shared__ float sh[Hh];
        sh[tid]       = hidden[b * Hh + tid];
        sh[tid + 256] = hidden[b * Hh + 256 + tid];
        __syncthreads();
        int a = tid;
        const float* wrow = W1 + (size_t)a * (Mm + Hh) + Mm;
        float acc = b1[a];
        #pragma unroll 8
        for (int h = 0; h < Hh; h += 4) {
            f32x4 w = *reinterpret_cast<const f32x4*>(wrow + h);
            acc += w[0] * sh[h] + w[1] * sh[h + 1] + w[2] * sh[h + 2] + w[3] * sh[h + 3];
        }
        hb[b * Aa + a] = acc;
    }
}

// ---------------- k_score: fused score GEMM (dbuf LDS, prefetch-2 A) -------
// score[b,l] = sum_a tanh( mem[b,l,:].W1m[a,:] + hb[b,a] ) * W2[a]
// Grid 1024 x 256 thr (4 waves). Block tile BM=64 rows, BN=256, BK=32.
__launch_bounds__(256, 4)
__global__ void k_score(const float* __restrict__ mem,
                        const unsigned short* __restrict__ W1mb,
                        const float* __restrict__ hb, const float* __restrict__ W2,
                        float* __restrict__ score) {
    __shared__ unsigned short ldsA[2][64 * 32];    // 4KB each: [row][k] bf16
    __shared__ unsigned short ldsB[2][256 * 32];   // 16KB each: [a][k] bf16

    const int tid  = threadIdx.x;
    const int wave = tid >> 6;
    const int lane = tid & 63;
    const int g = lane >> 4;                       // k-group 0..3
    const int r = lane & 15;                       // own-dim index
    const int blockRow = blockIdx.x * 64;
    const int b = blockRow >> 11;                  // 2048 rows per batch

    f32x4 acc[16];
    #pragma unroll
    for (int ct = 0; ct < 16; ct++) acc[ct] = (f32x4){0.f, 0.f, 0.f, 0.f};

    // A staging: 64 rows x 32 fp32 = 512 chunks of 16B; thread handles c0,c1
    const int c0 = tid, c1 = tid + 256;
    const float* gA0 = mem + (size_t)(blockRow + (c0 >> 3)) * Mm + (c0 & 7) * 4;
    const float* gA1 = mem + (size_t)(blockRow + (c1 >> 3)) * Mm + (c1 & 7) * 4;
    const char* gB = (const char*)W1mb;            // permuted: step ks at byte ks*16384

    // prologue: stage ks=0; preload A(1) into regs
    {
        #pragma unroll
        for (int j = 0; j < 4; ++j)
            gload_lds16(gB + (size_t)(wave * 4 + j) * 1024 + lane * 16,
                        &ldsB[0][(wave * 4 + j) * 512]);
        f32x4 a0 = *reinterpret_cast<const f32x4*>(gA0);
        f32x4 a1 = *reinterpret_cast<const f32x4*>(gA1);
        *reinterpret_cast<ushort4v*>(&ldsA[0][c0 * 4]) = cvt4(a0);
        *reinterpret_cast<ushort4v*>(&ldsA[0][c1 * 4]) = cvt4(a1);
    }
    f32x4 p0 = *reinterpret_cast<const f32x4*>(gA0 + 32);
    f32x4 p1 = *reinterpret_cast<const f32x4*>(gA1 + 32);
    __syncthreads();

    for (int ks = 0; ks < 16; ++ks) {
        const int cur = ks & 1, nxt = cur ^ 1;
        // stage next tile first (prev compute's readers of [nxt] finished at the barrier)
        if (ks < 15) {
            #pragma unroll
            for (int j = 0; j < 4; ++j)
                gload_lds16(gB + (size_t)(ks + 1) * 16384 + (wave * 4 + j) * 1024 + lane * 16,
                            &ldsB[nxt][(wave * 4 + j) * 512]);
            *reinterpret_cast<ushort4v*>(&ldsA[nxt][c0 * 4]) = cvt4(p0);
            *reinterpret_cast<ushort4v*>(&ldsA[nxt][c1 * 4]) = cvt4(p1);
        }
        // prefetch A(ks+2) into regs — a full iteration ahead of its LDS write
        if (ks < 14) {
            p0 = *reinterpret_cast<const f32x4*>(gA0 + (ks + 2) * 32);
            p1 = *reinterpret_cast<const f32x4*>(gA1 + (ks + 2) * 32);
        }
        // compute current tile
        short8 af = *reinterpret_cast<const short8*>(&ldsA[cur][(wave * 16 + r) * 32 + g * 8]);
        #pragma unroll
        for (int h = 0; h < 4; ++h) {
            short8 bf[4];
            #pragma unroll
            for (int j = 0; j < 4; ++j)
                bf[j] = *reinterpret_cast<const short8*>(&ldsB[cur][((h * 4 + j) * 16 + r) * 32 + g * 8]);
            #pragma unroll
            for (int j = 0; j < 4; ++j)
                acc[h * 4 + j] = __builtin_amdgcn_mfma_f32_16x16x32_bf16(af, bf[j], acc[h * 4 + j], 0, 0, 0);
        }
        __syncthreads();
    }

    // Epilogue: C/D layout col=lane&15 (a), row=(lane>>4)*4+reg (l within tile)
    float s[4] = {0.f, 0.f, 0.f, 0.f};
    #pragma unroll
    for (int ct = 0; ct < 16; ++ct) {
        int a = ct * 16 + r;
        float hba = hb[b * Aa + a];
        float w2a = W2[a];
        #pragma unroll
        for (int reg = 0; reg < 4; ++reg) {
            float pr = acc[ct][reg] + hba;
            float e = __expf(2.f * pr);
            float t = (e - 1.f) * __builtin_amdgcn_rcpf(e + 1.f);
            s[reg] += t * w2a;
        }
    }
    #pragma unroll
    for (int off = 1; off < 16; off <<= 1) {
        #pragma unroll
        for (int reg = 0; reg < 4; ++reg) s[reg] += __shfl_xor(s[reg], off, 64);
    }
    if (r == 0) {
        #pragma unroll
        for (int reg = 0; reg < 4; ++reg)
            score[blockRow + wave * 16 + g * 4 + reg] = s[reg];
    }
}

// ---------------- k_exp1: fused softmax + weighted partial sums ------------
// Block (b, lc): recompute row-softmax stats from L2-resident score, write
// p for its own 32 rows, and accumulate partial[b*64+lc][m] = sum p*mem.
__launch_bounds__(256)
__global__ void k_exp1(const float* __restrict__ mem, const float* __restrict__ score,
                       const int* __restrict__ mask,
                       float* __restrict__ p, float* __restrict__ partial) {
    const int b   = blockIdx.x >> 6;
    const int lc  = blockIdx.x & 63;               // 64 chunks of 32 l
    const int tid = threadIdx.x;
    const int wave = tid >> 6;
    __shared__ float redmx[4];
    __shared__ float redsm[4];
    __shared__ float sp[32];
    __shared__ f32x4 sacc[128];

    const float* sb = score + b * Ll;
    const int*   mb = mask + b * Ll;

    // ---- stats over the FULL row (identical arithmetic in all 64 blocks) ----
    float v[8]; int mk[8];
    #pragma unroll
    for (int i = 0; i < 8; i++) {
        int l = i * 256 + tid;
        v[i]  = sb[l];
        mk[i] = mb[l];
    }
    float mx = -1e30f;
    #pragma unroll
    for (int i = 0; i < 8; i++) if (mk[i]) mx = fmaxf(mx, v[i]);
    #pragma unroll
    for (int off = 1; off < 64; off <<= 1) mx = fmaxf(mx, __shfl_xor(mx, off, 64));
    if ((tid & 63) == 0) redmx[wave] = mx;
    __syncthreads();
    mx = fmaxf(fmaxf(redmx[0], redmx[1]), fmaxf(redmx[2], redmx[3]));

    float s = 0.f;
    #pragma unroll
    for (int i = 0; i < 8; i++) s += mk[i] ? __expf(v[i] - mx) : 0.f;
    #pragma unroll
    for (int off = 1; off < 64; off <<= 1) s += __shfl_xor(s, off, 64);
    if ((tid & 63) == 0) redsm[wave] = s;
    __syncthreads();
    s = redsm[0] + redsm[1] + redsm[2] + redsm[3];
    const float inv = 1.f / s;

    // ---- p for our own 32 rows ----
    if (tid < 32) {
        int l = lc * 32 + tid;
        float pv = mb[l] ? __expf(sb[l] - mx) * inv : 0.f;
        sp[tid] = pv;
        p[b * Ll + l] = pv;
    }
    __syncthreads();

    // ---- weighted sum: 128 threads cover a full 2KB row, 2 row-streams ----
    const int half = tid >> 7, cq = tid & 127;
    const float* base = mem + ((size_t)b * Ll + lc * 32) * Mm + cq * 4;
    f32x4 acc = (f32x4){0.f, 0.f, 0.f, 0.f};
    for (int rr = half; rr < 32; rr += 2)
        acc += sp[rr] * *reinterpret_cast<const f32x4*>(base + (size_t)rr * Mm);
    if (half == 1) sacc[cq] = acc;
    __syncthreads();
    if (half == 0) {
        acc += sacc[cq];
        *reinterpret_cast<f32x4*>(partial + (size_t)blockIdx.x * Mm + cq * 4) = acc;
    }
}

// ---------------- k_exp2: reduce 64 partials per batch ---------------------
__global__ void k_exp2(const float* __restrict__ partial, float* __restrict__ out) {
    const int b  = blockIdx.x;                     // 32
    const int mi = threadIdx.x;                    // 128 threads, f32x4 each
    const float* pb = partial + (size_t)b * 64 * Mm + mi * 4;
    f32x4 acc = (f32x4){0.f, 0.f, 0.f, 0.f};
    #pragma unroll 8
    for (int c = 0; c < 64; ++c)
        acc += *reinterpret_cast<const f32x4*>(pb + (size_t)c * Mm);
    *reinterpret_cast<f32x4*>(out + b * Mm + mi * 4) = acc;
}

extern "C" void kernel_launch(void* const* d_in, const int* in_sizes, int n_in,
                              void* d_out, int out_size, void* d_ws, size_t ws_size,
                              hipStream_t stream) {
    const float* memory = (const float*)d_in[0];
    const float* hidden = (const float*)d_in[1];
    const int*   mask   = (const int*)d_in[2];
    const float* W1     = (const float*)d_in[3];
    const float* b1     = (const float*)d_in[4];
    const float* W2     = (const float*)d_in[5];
    // b2 (d_in[6]) is a constant shift -> cancels in softmax.
    float* out = (float*)d_out;

    // ws: [0,256K) W1m bf16 perm | [256K,288K) hb | [288K,544K) score | [1M,5M) partial
    unsigned short* W1mb = (unsigned short*)d_ws;
    float* hb      = (float*)((char*)d_ws + 256 * 1024);
    float* score   = (float*)((char*)d_ws + 288 * 1024);
    float* partial = (float*)((char*)d_ws + 1024 * 1024);
    float* p = out + Bb * Mm;                      // p_memory region of d_out

    k_prep<<<160, 256, 0, stream>>>(W1, hidden, b1, W1mb, hb);
    k_score<<<1024, 256, 0, stream>>>(memory, W1mb, hb, W2, score);
    k_exp1<<<2048, 256, 0, stream>>>(memory, score, mask, p, partial);
    k_exp2<<<32, 128, 0, stream>>>(partial, out);
}

// Round 6
// 254.054 us; speedup vs baseline: 1.0102x; 1.0102x over previous
//
#include <hip/hip_runtime.h>
#include <hip/hip_bf16.h>

// Sizes fixed by the problem
constexpr int Bb = 32;
constexpr int Ll = 2048;
constexpr int Mm = 512;
constexpr int Hh = 512;
constexpr int Aa = 256;

typedef __attribute__((ext_vector_type(4))) float f32x4;
typedef __attribute__((ext_vector_type(16))) float f32x16;
typedef __attribute__((ext_vector_type(8))) short short8;
typedef __attribute__((ext_vector_type(4))) unsigned short ushort4v;

__device__ __forceinline__ unsigned short f2bf(float f) {
    __hip_bfloat16 h = __float2bfloat16(f);   // RNE
    return *reinterpret_cast<unsigned short*>(&h);
}

__device__ __forceinline__ ushort4v cvt4(f32x4 v) {
    ushort4v o;
    o[0] = f2bf(v[0]); o[1] = f2bf(v[1]); o[2] = f2bf(v[2]); o[3] = f2bf(v[3]);
    return o;
}

// async global->LDS, 16B per lane; lds dest is wave-uniform base (+lane*16 by HW)
__device__ __forceinline__ void gload_lds16(const void* g, void* l) {
    __builtin_amdgcn_global_load_lds(
        (const __attribute__((address_space(1))) unsigned int*)g,
        (__attribute__((address_space(3))) unsigned int*)l, 16, 0, 0);
}

// ---------------- k_prep: fused W1m->bf16 permute + hb precompute ----------
// blocks 0..127: W1[:, :512] -> bf16, layout [ks][a][32] with the k_score
//   LDS XOR-swizzle BAKED IN (pre-swizzled source for global_load_lds):
//   elem = ks*8192 + a*32 + (kb ^ ((a&3)<<3))
// blocks 128..159: hb[b][a] = hidden[b,:].W1[a,512:] + b1[a]
__global__ void k_prep(const float* __restrict__ W1, const float* __restrict__ hidden,
                       const float* __restrict__ b1,
                       unsigned short* __restrict__ W1mb, float* __restrict__ hb) {
    const int tid = threadIdx.x;
    if (blockIdx.x < 128) {
        int i = blockIdx.x * 256 + tid;            // 32768 threads, 4 floats each
        int a  = i >> 7;                           // 128 float4 per row
        int mq = (i & 127) << 2;
        f32x4 v = *reinterpret_cast<const f32x4*>(W1 + (size_t)a * (Mm + Hh) + mq);
        int ks = mq >> 5;                          // K-step (32 k per step)
        int kb = mq & 31;
        int kswz = kb ^ ((a & 3) << 3);            // LDS bank swizzle, pre-applied
        *reinterpret_cast<ushort4v*>(W1mb + (size_t)ks * (Aa * 32) + a * 32 + kswz) = cvt4(v);
    } else {
        int b = blockIdx.x - 128;
        __shared__ float sh[Hh];
        sh[tid]       = hidden[b * Hh + tid];
        sh[tid + 256] = hidden[b * Hh + 256 + tid];
        __syncthreads();
        int a = tid;
        const float* wrow = W1 + (size_t)a * (Mm + Hh) + Mm;
        float acc = b1[a];
        #pragma unroll 8
        for (int h = 0; h < Hh; h += 4) {
            f32x4 w = *reinterpret_cast<const f32x4*>(wrow + h);
            acc += w[0] * sh[h] + w[1] * sh[h + 1] + w[2] * sh[h + 2] + w[3] * sh[h + 3];
        }
        hb[b * Aa + a] = acc;
    }
}

// ---------------- k_score: fused score GEMM, 32x32x16 MFMA, swizzled LDS ---
// score[b,l] = sum_a tanh( mem[b,l,:].W1m[a,:] + hb[b,a] ) * W2[a]
// Grid 1024 x 256 thr (4 waves). Block: BM=64 rows, BN=256 cols, BK=32.
// Wave w: 2x2 tiles of 32x32 -> rows 0..63 x cols [w*64, w*64+64).
__launch_bounds__(256, 4)
__global__ void k_score(const float* __restrict__ mem,
                        const unsigned short* __restrict__ W1mb,
                        const float* __restrict__ hb, const float* __restrict__ W2,
                        float* __restrict__ score) {
    __shared__ unsigned short ldsA[2][64 * 32];    // 4KB each, [row][k^swz]
    __shared__ unsigned short ldsB[2][256 * 32];   // 16KB each, [a][k^swz]

    const int tid  = threadIdx.x;
    const int wave = tid >> 6;
    const int lane = tid & 63;
    const int l31  = lane & 31;
    const int hi   = lane >> 5;
    const int blockRow = blockIdx.x * 64;
    const int b = blockRow >> 11;                  // 2048 rows per batch

    f32x16 acc[2][2];
    #pragma unroll
    for (int i = 0; i < 2; i++)
        #pragma unroll
        for (int j = 0; j < 2; j++)
            #pragma unroll
            for (int e = 0; e < 16; e++) acc[i][j][e] = 0.f;

    // A staging: 64 rows x 32 fp32; thread handles chunks c0, c1 (4 floats each)
    const int c0 = tid, c1 = tid + 256;
    const int ar0 = c0 >> 3, ak0 = (c0 & 7) * 4;
    const int ar1 = c1 >> 3, ak1 = (c1 & 7) * 4;
    const int sa0 = ar0 * 32 + (ak0 ^ ((ar0 & 3) << 3));
    const int sa1 = ar1 * 32 + (ak1 ^ ((ar1 & 3) << 3));
    const float* gA0 = mem + (size_t)(blockRow + ar0) * Mm + ak0;
    const float* gA1 = mem + (size_t)(blockRow + ar1) * Mm + ak1;
    const char* gB = (const char*)W1mb;            // pre-swizzled; step ks at byte ks*16384

    // fragment read offsets (elems), swizzle folded in
    const int swz = (l31 & 3) << 3;
    const int aoff0 = (hi * 8) ^ swz;              // kk=0
    const int aoff1 = (hi * 8 + 16) ^ swz;         // kk=1
    const int arow0 = l31 * 32;
    const int arow1 = (32 + l31) * 32;
    const int brow0 = (wave * 64 + l31) * 32;
    const int brow1 = (wave * 64 + 32 + l31) * 32;

    // prologue: stage ks=0; preload A(1) into regs
    #pragma unroll
    for (int j = 0; j < 4; ++j)
        gload_lds16(gB + (size_t)(wave * 4 + j) * 1024 + lane * 16,
                    &ldsB[0][(wave * 4 + j) * 512]);
    {
        f32x4 a0 = *reinterpret_cast<const f32x4*>(gA0);
        f32x4 a1 = *reinterpret_cast<const f32x4*>(gA1);
        *reinterpret_cast<ushort4v*>(&ldsA[0][sa0]) = cvt4(a0);
        *reinterpret_cast<ushort4v*>(&ldsA[0][sa1]) = cvt4(a1);
    }
    f32x4 p0 = *reinterpret_cast<const f32x4*>(gA0 + 32);
    f32x4 p1 = *reinterpret_cast<const f32x4*>(gA1 + 32);
    __syncthreads();

    for (int ks = 0; ks < 16; ++ks) {
        const int cur = ks & 1, nxt = cur ^ 1;
        if (ks < 15) {
            #pragma unroll
            for (int j = 0; j < 4; ++j)
                gload_lds16(gB + (size_t)(ks + 1) * 16384 + (wave * 4 + j) * 1024 + lane * 16,
                            &ldsB[nxt][(wave * 4 + j) * 512]);
            *reinterpret_cast<ushort4v*>(&ldsA[nxt][sa0]) = cvt4(p0);
            *reinterpret_cast<ushort4v*>(&ldsA[nxt][sa1]) = cvt4(p1);
        }
        if (ks < 14) {
            p0 = *reinterpret_cast<const f32x4*>(gA0 + (ks + 2) * 32);
            p1 = *reinterpret_cast<const f32x4*>(gA1 + (ks + 2) * 32);
        }
        const unsigned short* A  = ldsA[cur];
        const unsigned short* Bt = ldsB[cur];
        #pragma unroll
        for (int kk = 0; kk < 2; ++kk) {
            const int ao = kk ? aoff1 : aoff0;
            short8 a0 = *reinterpret_cast<const short8*>(&A[arow0 + ao]);
            short8 a1 = *reinterpret_cast<const short8*>(&A[arow1 + ao]);
            short8 b0 = *reinterpret_cast<const short8*>(&Bt[brow0 + ao]);
            short8 b1 = *reinterpret_cast<const short8*>(&Bt[brow1 + ao]);
            acc[0][0] = __builtin_amdgcn_mfma_f32_32x32x16_bf16(a0, b0, acc[0][0], 0, 0, 0);
            acc[0][1] = __builtin_amdgcn_mfma_f32_32x32x16_bf16(a0, b1, acc[0][1], 0, 0, 0);
            acc[1][0] = __builtin_amdgcn_mfma_f32_32x32x16_bf16(a1, b0, acc[1][0], 0, 0, 0);
            acc[1][1] = __builtin_amdgcn_mfma_f32_32x32x16_bf16(a1, b1, acc[1][1], 0, 0, 0);
        }
        __syncthreads();
    }

    // Epilogue. C/D (32x32): col = lane&31, row = (rg&3) + 8*(rg>>2) + 4*hi.
    float sc[2][16];
    #pragma unroll
    for (int tr = 0; tr < 2; tr++)
        #pragma unroll
        for (int rg = 0; rg < 16; rg++) sc[tr][rg] = 0.f;
    #pragma unroll
    for (int tc = 0; tc < 2; ++tc) {
        int a = wave * 64 + tc * 32 + l31;
        float hba = hb[b * Aa + a];
        float w2a = W2[a];
        #pragma unroll
        for (int tr = 0; tr < 2; tr++)
            #pragma unroll
            for (int rg = 0; rg < 16; rg++) {
                float pr = acc[tr][tc][rg] + hba;
                float e = __expf(2.f * pr);
                float t = (e - 1.f) * __builtin_amdgcn_rcpf(e + 1.f);
                sc[tr][rg] += t * w2a;
            }
    }
    // reduce over the 32 cols (lanes within each half-wave)
    #pragma unroll
    for (int off = 1; off < 32; off <<= 1)
        #pragma unroll
        for (int tr = 0; tr < 2; tr++)
            #pragma unroll
            for (int rg = 0; rg < 16; rg++)
                sc[tr][rg] += __shfl_xor(sc[tr][rg], off, 64);
    float* sred = (float*)&ldsA[0][0];             // reuse: 64 rows x 4 waves
    if (l31 == 0) {
        #pragma unroll
        for (int tr = 0; tr < 2; tr++)
            #pragma unroll
            for (int rg = 0; rg < 16; rg++) {
                int row = tr * 32 + (rg & 3) + 8 * (rg >> 2) + 4 * hi;
                sred[row * 4 + wave] = sc[tr][rg];
            }
    }
    __syncthreads();
    if (tid < 64)
        score[blockRow + tid] = sred[tid * 4] + sred[tid * 4 + 1]
                              + sred[tid * 4 + 2] + sred[tid * 4 + 3];
}

// ---------------- k_exp1: fused softmax + weighted partial sums ------------
// Block (b, lc): recompute row-softmax stats from cached score, write p for
// its 64 rows, accumulate partial[b*32+lc][m] = sum_l p*mem.
__launch_bounds__(256)
__global__ void k_exp1(const float* __restrict__ mem, const float* __restrict__ score,
                       const int* __restrict__ mask,
                       float* __restrict__ p, float* __restrict__ partial) {
    const int b   = blockIdx.x >> 5;
    const int lc  = blockIdx.x & 31;               // 32 chunks of 64 l
    const int tid = threadIdx.x;
    const int wave = tid >> 6;
    __shared__ float redmx[4];
    __shared__ float redsm[4];
    __shared__ float sp[64];
    __shared__ f32x4 sacc[128];

    const float* sb = score + b * Ll;
    const int*   mb = mask + b * Ll;

    // ---- stats over the FULL row (identical arithmetic in all 32 blocks) ----
    float v[8]; int mk[8];
    #pragma unroll
    for (int i = 0; i < 8; i++) {
        int l = i * 256 + tid;
        v[i]  = sb[l];
        mk[i] = mb[l];
    }
    float mx = -1e30f;
    #pragma unroll
    for (int i = 0; i < 8; i++) if (mk[i]) mx = fmaxf(mx, v[i]);
    #pragma unroll
    for (int off = 1; off < 64; off <<= 1) mx = fmaxf(mx, __shfl_xor(mx, off, 64));
    if ((tid & 63) == 0) redmx[wave] = mx;
    __syncthreads();
    mx = fmaxf(fmaxf(redmx[0], redmx[1]), fmaxf(redmx[2], redmx[3]));

    float s = 0.f;
    #pragma unroll
    for (int i = 0; i < 8; i++) s += mk[i] ? __expf(v[i] - mx) : 0.f;
    #pragma unroll
    for (int off = 1; off < 64; off <<= 1) s += __shfl_xor(s, off, 64);
    if ((tid & 63) == 0) redsm[wave] = s;
    __syncthreads();
    s = redsm[0] + redsm[1] + redsm[2] + redsm[3];
    const float inv = 1.f / s;

    // ---- p for our own 64 rows ----
    if (tid < 64) {
        int l = lc * 64 + tid;
        float pv = mb[l] ? __expf(sb[l] - mx) * inv : 0.f;
        sp[tid] = pv;
        p[b * Ll + l] = pv;
    }
    __syncthreads();

    // ---- weighted sum: 128 threads cover a full 2KB row, 2 row-streams ----
    const int half = tid >> 7, cq = tid & 127;
    const float* base = mem + ((size_t)b * Ll + lc * 64) * Mm + cq * 4;
    f32x4 acc = (f32x4){0.f, 0.f, 0.f, 0.f};
    #pragma unroll 8
    for (int rr = half; rr < 64; rr += 2)
        acc += sp[rr] * *reinterpret_cast<const f32x4*>(base + (size_t)rr * Mm);
    if (half == 1) sacc[cq] = acc;
    __syncthreads();
    if (half == 0) {
        acc += sacc[cq];
        *reinterpret_cast<f32x4*>(partial + (size_t)blockIdx.x * Mm + cq * 4) = acc;
    }
}

// ---------------- k_exp2: reduce 32 partials per batch ---------------------
__global__ void k_exp2(const float* __restrict__ partial, float* __restrict__ out) {
    const int b  = blockIdx.x;                     // 32
    const int mi = threadIdx.x;                    // 128 threads, f32x4 each
    const float* pb = partial + (size_t)b * 32 * Mm + mi * 4;
    f32x4 acc = (f32x4){0.f, 0.f, 0.f, 0.f};
    #pragma unroll 8
    for (int c = 0; c < 32; ++c)
        acc += *reinterpret_cast<const f32x4*>(pb + (size_t)c * Mm);
    *reinterpret_cast<f32x4*>(out + b * Mm + mi * 4) = acc;
}

extern "C" void kernel_launch(void* const* d_in, const int* in_sizes, int n_in,
                              void* d_out, int out_size, void* d_ws, size_t ws_size,
                              hipStream_t stream) {
    const float* memory = (const float*)d_in[0];
    const float* hidden = (const float*)d_in[1];
    const int*   mask   = (const int*)d_in[2];
    const float* W1     = (const float*)d_in[3];
    const float* b1     = (const float*)d_in[4];
    const float* W2     = (const float*)d_in[5];
    // b2 (d_in[6]) is a constant shift -> cancels in softmax.
    float* out = (float*)d_out;

    // ws: [0,256K) W1m bf16 swizzled | [256K,288K) hb | [288K,544K) score | [1M,3M) partial
    unsigned short* W1mb = (unsigned short*)d_ws;
    float* hb      = (float*)((char*)d_ws + 256 * 1024);
    float* score   = (float*)((char*)d_ws + 288 * 1024);
    float* partial = (float*)((char*)d_ws + 1024 * 1024);
    float* p = out + Bb * Mm;                      // p_memory region of d_out

    k_prep<<<160, 256, 0, stream>>>(W1, hidden, b1, W1mb, hb);
    k_score<<<1024, 256, 0, stream>>>(memory, W1mb, hb, W2, score);
    k_exp1<<<1024, 256, 0, stream>>>(memory, score, mask, p, partial);
    k_exp2<<<32, 128, 0, stream>>>(partial, out);
}

// Round 7
// 241.207 us; speedup vs baseline: 1.0640x; 1.0533x over previous
//
#include <hip/hip_runtime.h>
#include <hip/hip_bf16.h>

// Sizes fixed by the problem
constexpr int Bb = 32;
constexpr int Ll = 2048;
constexpr int Mm = 512;
constexpr int Hh = 512;
constexpr int Aa = 256;

typedef __attribute__((ext_vector_type(4))) float f32x4;
typedef __attribute__((ext_vector_type(16))) float f32x16;
typedef __attribute__((ext_vector_type(8))) short short8;
typedef __attribute__((ext_vector_type(4))) unsigned short ushort4v;

__device__ __forceinline__ unsigned short f2bf(float f) {
    __hip_bfloat16 h = __float2bfloat16(f);   // RNE
    return *reinterpret_cast<unsigned short*>(&h);
}

__device__ __forceinline__ ushort4v cvt4(f32x4 v) {
    ushort4v o;
    o[0] = f2bf(v[0]); o[1] = f2bf(v[1]); o[2] = f2bf(v[2]); o[3] = f2bf(v[3]);
    return o;
}

// async global->LDS, 16B per lane; lds dest is wave-uniform base (+lane*16 by HW)
__device__ __forceinline__ void gload_lds16(const void* g, void* l) {
    __builtin_amdgcn_global_load_lds(
        (const __attribute__((address_space(1))) unsigned int*)g,
        (__attribute__((address_space(3))) unsigned int*)l, 16, 0, 0);
}

// ---------------- k_prep: fused W1m->bf16 permute + hb precompute ----------
// blocks 0..127: W1[:, :512] -> bf16, layout [ks][a][32] with the k_main
//   LDS XOR-swizzle BAKED IN (pre-swizzled source for global_load_lds):
//   elem = ks*8192 + a*32 + (kb ^ ((a&3)<<3))
// blocks 128..159: hb[b][a] = hidden[b,:].W1[a,512:] + b1[a]
__global__ void k_prep(const float* __restrict__ W1, const float* __restrict__ hidden,
                       const float* __restrict__ b1,
                       unsigned short* __restrict__ W1mb, float* __restrict__ hb) {
    const int tid = threadIdx.x;
    if (blockIdx.x < 128) {
        int i = blockIdx.x * 256 + tid;            // 32768 threads, 4 floats each
        int a  = i >> 7;                           // 128 float4 per row
        int mq = (i & 127) << 2;
        f32x4 v = *reinterpret_cast<const f32x4*>(W1 + (size_t)a * (Mm + Hh) + mq);
        int ks = mq >> 5;                          // K-step (32 k per step)
        int kb = mq & 31;
        int kswz = kb ^ ((a & 3) << 3);            // LDS bank swizzle, pre-applied
        *reinterpret_cast<ushort4v*>(W1mb + (size_t)ks * (Aa * 32) + a * 32 + kswz) = cvt4(v);
    } else {
        int b = blockIdx.x - 128;
        __shared__ float sh[Hh];
        sh[tid]       = hidden[b * Hh + tid];
        sh[tid + 256] = hidden[b * Hh + 256 + tid];
        __syncthreads();
        int a = tid;
        const float* wrow = W1 + (size_t)a * (Mm + Hh) + Mm;
        float acc = b1[a];
        #pragma unroll 8
        for (int h = 0; h < Hh; h += 4) {
            f32x4 w = *reinterpret_cast<const f32x4*>(wrow + h);
            acc += w[0] * sh[h] + w[1] * sh[h + 1] + w[2] * sh[h + 2] + w[3] * sh[h + 3];
        }
        hb[b * Aa + a] = acc;
    }
}

// ---------------- k_main: score GEMM + local softmax + partial sums --------
// Per block (64 rows of (b,l)):
//   1) score GEMM (32x32x16 MFMA, dbuf swizzled LDS) as R6
//   2) chunk-local masked softmax: mx_c, w = e^(s-mx_c), sum_c
//   3) partial[chunk][m] = sum_rows w * mem[row][m]  (rows are L2/L3-hot)
// Global normalization deferred to k_final (flash-style).
__launch_bounds__(256, 4)
__global__ void k_main(const float* __restrict__ mem,
                       const unsigned short* __restrict__ W1mb,
                       const float* __restrict__ hb, const float* __restrict__ W2,
                       const int* __restrict__ mask,
                       float* __restrict__ wbuf, float* __restrict__ mxbuf,
                       float* __restrict__ smbuf, float* __restrict__ partial) {
    __shared__ unsigned short ldsA[2][64 * 32];    // 4KB each, [row][k^swz]
    __shared__ unsigned short ldsB[2][256 * 32];   // 16KB each, [a][k^swz]

    const int tid  = threadIdx.x;
    const int wave = tid >> 6;
    const int lane = tid & 63;
    const int l31  = lane & 31;
    const int hi   = lane >> 5;
    const int blockRow = blockIdx.x * 64;
    const int b = blockRow >> 11;                  // 2048 rows per batch

    f32x16 acc[2][2];
    #pragma unroll
    for (int i = 0; i < 2; i++)
        #pragma unroll
        for (int j = 0; j < 2; j++)
            #pragma unroll
            for (int e = 0; e < 16; e++) acc[i][j][e] = 0.f;

    // A staging: 64 rows x 32 fp32; thread handles chunks c0, c1 (4 floats each)
    const int c0 = tid, c1 = tid + 256;
    const int ar0 = c0 >> 3, ak0 = (c0 & 7) * 4;
    const int ar1 = c1 >> 3, ak1 = (c1 & 7) * 4;
    const int sa0 = ar0 * 32 + (ak0 ^ ((ar0 & 3) << 3));
    const int sa1 = ar1 * 32 + (ak1 ^ ((ar1 & 3) << 3));
    const float* gA0 = mem + (size_t)(blockRow + ar0) * Mm + ak0;
    const float* gA1 = mem + (size_t)(blockRow + ar1) * Mm + ak1;
    const char* gB = (const char*)W1mb;            // pre-swizzled; step ks at byte ks*16384

    // fragment read offsets (elems), swizzle folded in
    const int swz = (l31 & 3) << 3;
    const int aoff0 = (hi * 8) ^ swz;              // kk=0
    const int aoff1 = (hi * 8 + 16) ^ swz;         // kk=1
    const int arow0 = l31 * 32;
    const int arow1 = (32 + l31) * 32;
    const int brow0 = (wave * 64 + l31) * 32;
    const int brow1 = (wave * 64 + 32 + l31) * 32;

    // prologue: stage ks=0; preload A(1) into regs
    #pragma unroll
    for (int j = 0; j < 4; ++j)
        gload_lds16(gB + (size_t)(wave * 4 + j) * 1024 + lane * 16,
                    &ldsB[0][(wave * 4 + j) * 512]);
    {
        f32x4 a0 = *reinterpret_cast<const f32x4*>(gA0);
        f32x4 a1 = *reinterpret_cast<const f32x4*>(gA1);
        *reinterpret_cast<ushort4v*>(&ldsA[0][sa0]) = cvt4(a0);
        *reinterpret_cast<ushort4v*>(&ldsA[0][sa1]) = cvt4(a1);
    }
    f32x4 p0 = *reinterpret_cast<const f32x4*>(gA0 + 32);
    f32x4 p1 = *reinterpret_cast<const f32x4*>(gA1 + 32);
    __syncthreads();

    for (int ks = 0; ks < 16; ++ks) {
        const int cur = ks & 1, nxt = cur ^ 1;
        if (ks < 15) {
            #pragma unroll
            for (int j = 0; j < 4; ++j)
                gload_lds16(gB + (size_t)(ks + 1) * 16384 + (wave * 4 + j) * 1024 + lane * 16,
                            &ldsB[nxt][(wave * 4 + j) * 512]);
            *reinterpret_cast<ushort4v*>(&ldsA[nxt][sa0]) = cvt4(p0);
            *reinterpret_cast<ushort4v*>(&ldsA[nxt][sa1]) = cvt4(p1);
        }
        if (ks < 14) {
            p0 = *reinterpret_cast<const f32x4*>(gA0 + (ks + 2) * 32);
            p1 = *reinterpret_cast<const f32x4*>(gA1 + (ks + 2) * 32);
        }
        const unsigned short* A  = ldsA[cur];
        const unsigned short* Bt = ldsB[cur];
        #pragma unroll
        for (int kk = 0; kk < 2; ++kk) {
            const int ao = kk ? aoff1 : aoff0;
            short8 a0 = *reinterpret_cast<const short8*>(&A[arow0 + ao]);
            short8 a1 = *reinterpret_cast<const short8*>(&A[arow1 + ao]);
            short8 b0 = *reinterpret_cast<const short8*>(&Bt[brow0 + ao]);
            short8 b1 = *reinterpret_cast<const short8*>(&Bt[brow1 + ao]);
            acc[0][0] = __builtin_amdgcn_mfma_f32_32x32x16_bf16(a0, b0, acc[0][0], 0, 0, 0);
            acc[0][1] = __builtin_amdgcn_mfma_f32_32x32x16_bf16(a0, b1, acc[0][1], 0, 0, 0);
            acc[1][0] = __builtin_amdgcn_mfma_f32_32x32x16_bf16(a1, b0, acc[1][0], 0, 0, 0);
            acc[1][1] = __builtin_amdgcn_mfma_f32_32x32x16_bf16(a1, b1, acc[1][1], 0, 0, 0);
        }
        __syncthreads();
    }

    // ---- tanh + W2 epilogue. C/D (32x32): col=lane&31, row=(rg&3)+8*(rg>>2)+4*hi.
    float sc[2][16];
    #pragma unroll
    for (int tr = 0; tr < 2; tr++)
        #pragma unroll
        for (int rg = 0; rg < 16; rg++) sc[tr][rg] = 0.f;
    #pragma unroll
    for (int tc = 0; tc < 2; ++tc) {
        int a = wave * 64 + tc * 32 + l31;
        float hba = hb[b * Aa + a];
        float w2a = W2[a];
        #pragma unroll
        for (int tr = 0; tr < 2; tr++)
            #pragma unroll
            for (int rg = 0; rg < 16; rg++) {
                float pr = acc[tr][tc][rg] + hba;
                float e = __expf(2.f * pr);
                float t = (e - 1.f) * __builtin_amdgcn_rcpf(e + 1.f);
                sc[tr][rg] += t * w2a;
            }
    }
    #pragma unroll
    for (int off = 1; off < 32; off <<= 1)
        #pragma unroll
        for (int tr = 0; tr < 2; tr++)
            #pragma unroll
            for (int rg = 0; rg < 16; rg++)
                sc[tr][rg] += __shfl_xor(sc[tr][rg], off, 64);
    float* sred = (float*)&ldsA[0][0];             // 256 floats (reuse)
    float* sp   = (float*)&ldsA[1][0];             // 64 weights (reuse)
    f32x4* sacc = (f32x4*)&ldsB[0][0];             // 128 f32x4 (reuse)
    if (l31 == 0) {
        #pragma unroll
        for (int tr = 0; tr < 2; tr++)
            #pragma unroll
            for (int rg = 0; rg < 16; rg++) {
                int row = tr * 32 + (rg & 3) + 8 * (rg >> 2) + 4 * hi;
                sred[row * 4 + wave] = sc[tr][rg];
            }
    }
    __syncthreads();

    // ---- chunk-local masked softmax (wave 0 holds the 64 rows) ----
    if (tid < 64) {
        float sv = sred[tid * 4] + sred[tid * 4 + 1] + sred[tid * 4 + 2] + sred[tid * 4 + 3];
        int mk = mask[blockRow + tid];
        float mx = mk ? sv : -1e30f;
        #pragma unroll
        for (int off = 1; off < 64; off <<= 1) mx = fmaxf(mx, __shfl_xor(mx, off, 64));
        float w = mk ? __expf(sv - mx) : 0.f;
        float sm = w;
        #pragma unroll
        for (int off = 1; off < 64; off <<= 1) sm += __shfl_xor(sm, off, 64);
        sp[tid] = w;
        wbuf[blockRow + tid] = w;
        if (tid == 0) { mxbuf[blockIdx.x] = mx; smbuf[blockIdx.x] = sm; }
    }
    __syncthreads();

    // ---- unnormalized weighted sum over our 64 rows (rows are L2/L3-hot) ----
    const int half = tid >> 7, cq = tid & 127;
    const float* base = mem + (size_t)blockRow * Mm + cq * 4;
    f32x4 acc4 = (f32x4){0.f, 0.f, 0.f, 0.f};
    #pragma unroll 8
    for (int rr = half; rr < 64; rr += 2)
        acc4 += sp[rr] * *reinterpret_cast<const f32x4*>(base + (size_t)rr * Mm);
    if (half == 1) sacc[cq] = acc4;
    __syncthreads();
    if (half == 0) {
        acc4 += sacc[cq];
        *reinterpret_cast<f32x4*>(partial + (size_t)blockIdx.x * Mm + cq * 4) = acc4;
    }
}

// ---------------- k_final: global normalization ----------------------------
// Per batch b: MX = max_c mx_c, Z = sum_c e^(mx_c-MX)*sum_c,
//   p[l] = w[l] * e^(mx_c-MX)/Z,  expected[m] = sum_c e^(mx_c-MX)*partial_c[m]/Z
__global__ void k_final(const float* __restrict__ wbuf, const float* __restrict__ mxbuf,
                        const float* __restrict__ smbuf, const float* __restrict__ partial,
                        float* __restrict__ out, float* __restrict__ p) {
    const int b = blockIdx.x, tid = threadIdx.x;
    __shared__ float sf[32];
    if (tid < 32) {
        float mx = mxbuf[b * 32 + tid];
        float sm = smbuf[b * 32 + tid];
        float MX = mx;
        #pragma unroll
        for (int off = 1; off < 32; off <<= 1) MX = fmaxf(MX, __shfl_xor(MX, off, 64));
        float f = __expf(mx - MX);
        float z = f * sm;
        #pragma unroll
        for (int off = 1; off < 32; off <<= 1) z += __shfl_xor(z, off, 64);
        sf[tid] = f / z;
    }
    __syncthreads();
    const float* wb = wbuf + b * Ll;
    #pragma unroll
    for (int i = 0; i < 8; i++) {
        int l = i * 256 + tid;
        p[b * Ll + l] = wb[l] * sf[l >> 6];
    }
    if (tid < 128) {
        f32x4 acc = (f32x4){0.f, 0.f, 0.f, 0.f};
        #pragma unroll 8
        for (int c = 0; c < 32; ++c)
            acc += sf[c] * *reinterpret_cast<const f32x4*>(partial + ((size_t)(b * 32 + c)) * Mm + tid * 4);
        *reinterpret_cast<f32x4*>(out + b * Mm + tid * 4) = acc;
    }
}

extern "C" void kernel_launch(void* const* d_in, const int* in_sizes, int n_in,
                              void* d_out, int out_size, void* d_ws, size_t ws_size,
                              hipStream_t stream) {
    const float* memory = (const float*)d_in[0];
    const float* hidden = (const float*)d_in[1];
    const int*   mask   = (const int*)d_in[2];
    const float* W1     = (const float*)d_in[3];
    const float* b1     = (const float*)d_in[4];
    const float* W2     = (const float*)d_in[5];
    // b2 (d_in[6]) is a constant shift -> cancels in softmax.
    float* out = (float*)d_out;

    // ws: [0,256K) W1mb | [256K,288K) hb | [512K,768K) wbuf |
    //     [768K,772K) mxbuf | [772K,776K) smbuf | [1M,3M) partial
    unsigned short* W1mb = (unsigned short*)d_ws;
    float* hb      = (float*)((char*)d_ws + 256 * 1024);
    float* wbuf    = (float*)((char*)d_ws + 512 * 1024);
    float* mxbuf   = (float*)((char*)d_ws + 768 * 1024);
    float* smbuf   = (float*)((char*)d_ws + 772 * 1024);
    float* partial = (float*)((char*)d_ws + 1024 * 1024);
    float* p = out + Bb * Mm;                      // p_memory region of d_out

    k_prep<<<160, 256, 0, stream>>>(W1, hidden, b1, W1mb, hb);
    k_main<<<1024, 256, 0, stream>>>(memory, W1mb, hb, W2, mask,
                                     wbuf, mxbuf, smbuf, partial);
    k_final<<<32, 256, 0, stream>>>(wbuf, mxbuf, smbuf, partial, out, p);
}